// Round 1
// baseline (62.652 us; speedup 1.0000x reference)
//
#include <hip/hip_runtime.h>

// ---------------------------------------------------------------------------
// out[b,o] = sum_{f,p} x0[b,f]*x[b,p]*W[o,f,p] + bias[o]
//   == GEMM C[4096,256] = A[4096,16384] * W^T,  A[b, f*128+p] = x0[b,f]*x[b,p]
// Strategy: f16 MFMA GEMM (16x16x32), A built on the fly, split-K=8 + f32
// atomics, W/x/x0 pre-converted to f16 in d_ws with pre-swizzled 16B segs so
// linear global_load_lds staging + XOR'd ds_read_b128 is bank-conflict-free.
// ---------------------------------------------------------------------------

typedef _Float16 f16x8 __attribute__((ext_vector_type(8)));
typedef float    f32x4 __attribute__((ext_vector_type(4)));

#define B_SZ   4096
#define O_SZ   256
#define K_SZ   16384   // FIELD*H_PREV = 128*128
#define SPLITK 8
#define KCHUNK 2048    // K_SZ / SPLITK
#define BKSTEP 64
#define NSTEPS 32      // KCHUNK / BKSTEP

// ws layout (f16):
//   Wf  : [256][16384]  seg-swizzled   = 8388608 B
//   Xf  : [4096][128]   seg-swizzled   = 1048576 B
//   X0f : [4096][128]   linear         = 1048576 B
#define WS_WF_OFF  0
#define WS_XF_OFF  8388608
#define WS_X0_OFF  9437184
#define WS_NEEDED  10485760

__device__ __forceinline__ void gl_lds16(const void* g, void* l) {
  __builtin_amdgcn_global_load_lds(
      (const __attribute__((address_space(1))) void*)g,
      (__attribute__((address_space(3))) void*)l, 16, 0, 0);
}

// ------------------------------ prep kernel --------------------------------
// unit ranges: [0,524288) W 8-elem groups; [524288,589824) x 8-elem groups;
// [589824,655360) x0 8-elem groups; [655360,917504) out-init float4 groups.
__global__ __launch_bounds__(256) void prep_kernel(
    const float* __restrict__ x0, const float* __restrict__ x,
    const float* __restrict__ W, const float* __restrict__ bias,
    _Float16* __restrict__ Wf, _Float16* __restrict__ Xf,
    _Float16* __restrict__ X0f, float* __restrict__ out)
{
  int i = blockIdx.x * 256 + threadIdx.x;
  if (i < 524288) {
    // W convert + seg swizzle within each 64-elem (BK) window
    int o  = i >> 11;          // 2048 groups of 8 per row
    int k8 = i & 2047;
    int kk  = k8 >> 3;
    int seg = k8 & 7;
    const float* s = W + ((size_t)o << 14) + ((size_t)k8 << 3);
    f16x8 h;
#pragma unroll
    for (int e = 0; e < 8; ++e) h[e] = (_Float16)s[e];
    int segp = seg ^ (o & 7);
    *(f16x8*)(Wf + ((size_t)o << 14) + kk * 64 + segp * 8) = h;
  } else if (i < 589824) {
    // x convert + seg swizzle (16 segs/row, XOR affects low 3 bits)
    int j = i - 524288;
    int r = j >> 4, seg = j & 15;
    const float* s = x + r * 128 + seg * 8;
    f16x8 h;
#pragma unroll
    for (int e = 0; e < 8; ++e) h[e] = (_Float16)s[e];
    int segp = seg ^ (r & 7);
    *(f16x8*)(Xf + r * 128 + segp * 8) = h;
  } else if (i < 655360) {
    // x0 convert, linear
    int j = i - 589824;
    const float* s = x0 + (size_t)j * 8;
    f16x8 h;
#pragma unroll
    for (int e = 0; e < 8; ++e) h[e] = (_Float16)s[e];
    *(f16x8*)(X0f + (size_t)j * 8) = h;
  } else {
    // out = bias (broadcast over rows); also the split-K accumulator base
    int j = i - 655360;                 // float4 index into [4096][256]
    int c = (j * 4) & 255;
    float4 bv = *(const float4*)(bias + c);
    ((float4*)out)[j] = bv;
  }
}

// ------------------------------ GEMM kernel --------------------------------
// grid = 512: bid -> m = bid>>4 (32 row-blocks), g = bid&15, nb = g>>3 (2 col
// halves), sk = g&7 (split-K chunk). Same-(nb,sk) blocks land on one XCD.
// block = 256 thr = 4 waves (2x2), wave = 64x64 out, acc = 4x4 frags 16x16.
__global__ __launch_bounds__(256, 2) void gemm_kernel(
    const _Float16* __restrict__ Wf, const _Float16* __restrict__ Xf,
    const _Float16* __restrict__ X0f, float* __restrict__ out)
{
  __shared__ __align__(16) _Float16 x_s[128 * 128];      // 32 KB, swizzled
  __shared__ __align__(16) _Float16 x0_s[128 * 16];      // 4 KB, linear
  __shared__ __align__(16) _Float16 w_s[2][128 * 64];    // 2x16 KB, swizzled

  const int bid = blockIdx.x;
  const int mb  = bid >> 4;
  const int g   = bid & 15;
  const int nb  = g >> 3;
  const int sk  = g & 7;

  const int tid  = threadIdx.x;
  const int lane = tid & 63;
  const int wv   = tid >> 6;
  const int wr   = (wv >> 1) * 64;   // wave row offset in 128-tile
  const int wc   = (wv & 1) * 64;    // wave col offset
  const int lr   = lane & 15;
  const int lg   = lane >> 4;        // 0..3 : k-subgroup
  const int swz  = lr & 7;

  // ---- prologue staging: x rows (32 KB linear copy; data pre-swizzled) ----
  const char* xsrc = (const char*)(Xf + ((size_t)mb << 14));   // mb*128*128
#pragma unroll
  for (int i = 0; i < 8; ++i)
    gl_lds16(xsrc + i * 4096 + tid * 16, (char*)x_s + i * 4096 + tid * 16);

  {  // x0 slice: rows mb*128.., cols sk*16..sk*16+16  -> [128][16]
    int r = tid >> 1, sg = tid & 1;
    const char* s0 =
        (const char*)(X0f + ((size_t)(mb * 128 + r)) * 128 + sk * 16 + sg * 8);
    gl_lds16(s0, (char*)x0_s + tid * 16);
  }

  // ---- W tile staging: [128 rows][64 f16 = 128 B], linear copy ----
  auto stageW = [&](int kk, int buf) {
#pragma unroll
    for (int i = 0; i < 4; ++i) {
      int d   = i * 4096 + tid * 16;
      int row = d >> 7;
      int off = d & 127;
      const char* src = (const char*)Wf +
          (((size_t)(nb * 128 + row) << 14) + sk * 2048 + kk * 64) * 2 + off;
      gl_lds16(src, (char*)w_s[buf] + d);
    }
  };

  stageW(0, 0);
  __syncthreads();   // drains all prologue global_load_lds (vmcnt0 + barrier)

  f32x4 acc[4][4] = {};
  _Float16 s_h[4];

#pragma unroll 2
  for (int kk = 0; kk < NSTEPS; ++kk) {
    const int buf = kk & 1;
    if (kk < NSTEPS - 1) stageW(kk + 1, buf ^ 1);   // issue loads early (T14)

    if ((kk & 1) == 0) {  // f changes every 2 K-steps (128/64)
      const int fl = kk >> 1;
#pragma unroll
      for (int mI = 0; mI < 4; ++mI)
        s_h[mI] = x0_s[(wr + mI * 16 + lr) * 16 + fl];
    }

#pragma unroll
    for (int t = 0; t < 2; ++t) {
      f16x8 av[4], bv[4];
#pragma unroll
      for (int mI = 0; mI < 4; ++mI) {
        const int row = wr + mI * 16 + lr;
        const int seg = ((kk & 1) * 8 + t * 4 + lg) ^ swz;
        f16x8 xv = *(const f16x8*)((const char*)x_s + row * 256 + seg * 16);
        av[mI] = xv * s_h[mI];          // 4x v_pk_mul_f16: A = x0 (x) x
      }
#pragma unroll
      for (int nI = 0; nI < 4; ++nI) {
        const int row = wc + nI * 16 + lr;
        const int seg = (t * 4 + lg) ^ swz;
        bv[nI] = *(const f16x8*)((const char*)w_s[buf] + row * 128 + seg * 16);
      }
#pragma unroll
      for (int mI = 0; mI < 4; ++mI)
#pragma unroll
        for (int nI = 0; nI < 4; ++nI)
          acc[mI][nI] = __builtin_amdgcn_mfma_f32_16x16x32_f16(
              av[mI], bv[nI], acc[mI][nI], 0, 0, 0);
    }
    __syncthreads();  // staging of kk+1 complete & all reads of buf done
  }

  // ---- epilogue: split-K accumulate into out (pre-initialized to bias) ----
  // C/D layout (m89): col = lane&15, row = (lane>>4)*4 + reg
  const int rbase = mb * 128 + wr + lg * 4;
  const int cbase = nb * 128 + wc + lr;
#pragma unroll
  for (int mI = 0; mI < 4; ++mI)
#pragma unroll
    for (int nI = 0; nI < 4; ++nI)
#pragma unroll
      for (int r = 0; r < 4; ++r) {
        int row = rbase + mI * 16 + r;
        int col = cbase + nI * 16;
        unsafeAtomicAdd(&out[(size_t)row * 256 + col], acc[mI][nI][r]);
      }
}

// --------------------------- fallback (no ws) ------------------------------
__global__ __launch_bounds__(256) void naive_kernel(
    const float* __restrict__ x0, const float* __restrict__ x,
    const float* __restrict__ W, const float* __restrict__ bias,
    float* __restrict__ out)
{
  __shared__ float x0_s[16][128];
  __shared__ float x_s[16][128];
  const int tid = threadIdx.x;
  const int b0  = blockIdx.x * 16;
  for (int i = tid; i < 16 * 128; i += 256) {
    int bb = i >> 7, c = i & 127;
    x0_s[bb][c] = x0[(size_t)(b0 + bb) * 128 + c];
    x_s[bb][c]  = x[(size_t)(b0 + bb) * 128 + c];
  }
  __syncthreads();
  const int lane = tid & 63, wv = tid >> 6;
  for (int o = wv; o < 256; o += 4) {
    float acc[16];
#pragma unroll
    for (int bb = 0; bb < 16; ++bb) acc[bb] = 0.f;
    for (int it = 0; it < 256; ++it) {
      int k = it * 64 + lane;
      float wval = W[(size_t)o * 16384 + k];
      int f = k >> 7, p = k & 127;
#pragma unroll
      for (int bb = 0; bb < 16; ++bb)
        acc[bb] += wval * (x0_s[bb][f] * x_s[bb][p]);
    }
#pragma unroll
    for (int bb = 0; bb < 16; ++bb) {
      float v = acc[bb];
      for (int off = 32; off; off >>= 1) v += __shfl_down(v, off);
      if (lane == 0) out[(size_t)(b0 + bb) * 256 + o] = v + bias[o];
    }
  }
}

// ------------------------------- launcher ----------------------------------
extern "C" void kernel_launch(void* const* d_in, const int* in_sizes, int n_in,
                              void* d_out, int out_size, void* d_ws,
                              size_t ws_size, hipStream_t stream)
{
  const float* x0   = (const float*)d_in[0];
  const float* x    = (const float*)d_in[1];
  const float* W    = (const float*)d_in[2];
  const float* bias = (const float*)d_in[3];
  float* out = (float*)d_out;

  if (ws_size >= (size_t)WS_NEEDED) {
    _Float16* Wf  = (_Float16*)((char*)d_ws + WS_WF_OFF);
    _Float16* Xf  = (_Float16*)((char*)d_ws + WS_XF_OFF);
    _Float16* X0f = (_Float16*)((char*)d_ws + WS_X0_OFF);
    prep_kernel<<<3584, 256, 0, stream>>>(x0, x, W, bias, Wf, Xf, X0f, out);
    gemm_kernel<<<512, 256, 0, stream>>>(Wf, Xf, X0f, out);
  } else {
    naive_kernel<<<256, 256, 0, stream>>>(x0, x, W, bias, out);
  }
}